// Round 2
// baseline (344.884 us; speedup 1.0000x reference)
//
#include <hip/hip_runtime.h>

// CapsNet forward, fp32.
// Kernel 0: transpose conv2 weights to [ci][kh][kw][co] for coalesced loads
// Kernel 1: conv1 9x9 VALID stride1: [B,1,28,28] -> [B,16,20,20]
// Kernel 2: conv2 9x9 VALID stride2, LDS-free, register-tiled -> u [B,144,8]
// Kernel 3: per-sample u_hat (LDS) + 3 routing iters + squash -> pred, v

__global__ __launch_bounds__(256) void transpose_w2(
    const float* __restrict__ w2, float* __restrict__ wT) {
  int idx = blockIdx.x * 256 + threadIdx.x;
  if (idx >= 41472) return;
  // idx = co*1296 + ci*81 + kh*9 + kw (coalesced read)
  int co = idx / 1296, r = idx % 1296;
  int ci = r / 81, r2 = r % 81, kh = r2 / 9, kw = r2 % 9;
  wT[(((ci * 9 + kh) * 9) + kw) * 32 + co] = w2[idx];
}

__global__ __launch_bounds__(320) void conv1_kernel(
    const float* __restrict__ in, const float* __restrict__ w,
    const float* __restrict__ bias, float* __restrict__ x1) {
  __shared__ __align__(16) float sIn[784];    // 28x28
  __shared__ float sW[1296];                  // 16x81
  int b = blockIdx.x, t = threadIdx.x;
  const float* inb = in + b * 784;
  for (int i = t; i < 784; i += 320) sIn[i] = inb[i];
  for (int i = t; i < 1296; i += 320) sW[i] = w[i];
  __syncthreads();
  int co = t / 20, oh = t % 20;   // 16*20 = 320 work items
  float bv = bias[co];
  float acc[20];
#pragma unroll
  for (int j = 0; j < 20; ++j) acc[j] = bv;
#pragma unroll
  for (int kh = 0; kh < 9; ++kh) {
    float r[28];
    const float4* row = (const float4*)&sIn[(oh + kh) * 28];
#pragma unroll
    for (int q = 0; q < 7; ++q) {
      float4 v = row[q];
      r[q * 4 + 0] = v.x; r[q * 4 + 1] = v.y; r[q * 4 + 2] = v.z; r[q * 4 + 3] = v.w;
    }
    const float* wr = &sW[co * 81 + kh * 9];
#pragma unroll
    for (int kw = 0; kw < 9; ++kw) {
      float wv = wr[kw];
#pragma unroll
      for (int j = 0; j < 20; ++j) acc[j] += wv * r[kw + j];
    }
  }
  float* outp = x1 + b * 6400 + co * 400 + oh * 20;
#pragma unroll
  for (int q = 0; q < 5; ++q) {
    *(float4*)&outp[q * 4] =
        make_float4(acc[q * 4], acc[q * 4 + 1], acc[q * 4 + 2], acc[q * 4 + 3]);
  }
}

// conv2: LDS-free. Thread = (sample, co, oh-triple h): 18 outputs.
// Weights from wT[ci][kh][kw][co] (coalesced over co-lanes, L1-resident).
// Input rows from x1 (2 unique 80B rows per wave-load, L1-resident).
__global__ __launch_bounds__(256) void conv2_kernel(
    const float* __restrict__ x1, const float* __restrict__ wT,
    const float* __restrict__ bias, float* __restrict__ u) {
  int t = threadIdx.x;
  int s = blockIdx.x * 4 + (t >> 6);
  int co = t & 31;
  int h = (t >> 5) & 1;             // oh = 3*h + ohi, ohi in [0,3)
  const float* xin = x1 + (size_t)s * 6400;
  float bv = bias[co];
  float acc[3][6];
#pragma unroll
  for (int i = 0; i < 3; ++i)
#pragma unroll
    for (int j = 0; j < 6; ++j) acc[i][j] = 0.0f;

  for (int ci = 0; ci < 16; ++ci) {
    const float* xc = xin + ci * 400;
#pragma unroll
    for (int kh = 0; kh < 9; ++kh) {
      float w[9];
      const float* wp = wT + ((ci * 9 + kh) * 9) * 32 + co;
#pragma unroll
      for (int kw = 0; kw < 9; ++kw) w[kw] = wp[kw * 32];
      float r[3][20];
#pragma unroll
      for (int ohi = 0; ohi < 3; ++ohi) {
        int ih = (3 * h + ohi) * 2 + kh;
        const float4* rp = (const float4*)(xc + ih * 20);
#pragma unroll
        for (int q = 0; q < 5; ++q) {
          float4 v = rp[q];
          r[ohi][q * 4 + 0] = v.x; r[ohi][q * 4 + 1] = v.y;
          r[ohi][q * 4 + 2] = v.z; r[ohi][q * 4 + 3] = v.w;
        }
      }
#pragma unroll
      for (int ohi = 0; ohi < 3; ++ohi) {
#pragma unroll
        for (int kw = 0; kw < 9; ++kw) {
          float wv = w[kw];
#pragma unroll
          for (int ow = 0; ow < 6; ++ow)
            acc[ohi][ow] += wv * r[ohi][ow * 2 + kw];
        }
      }
    }
  }
  // u[b, (co&3)*36 + oh*6 + ow, co>>2]
  float* ub = u + (size_t)s * 1152;
  int c8 = co >> 2;
  int ib = (co & 3) * 36;
#pragma unroll
  for (int ohi = 0; ohi < 3; ++ohi) {
    int oh = 3 * h + ohi;
#pragma unroll
    for (int ow = 0; ow < 6; ++ow)
      ub[(ib + oh * 6 + ow) * 8 + c8] = acc[ohi][ow] + bv;
  }
}

__global__ __launch_bounds__(512) void routing_kernel(
    const float* __restrict__ u, const float* __restrict__ W,
    float* __restrict__ out, int B) {
  __shared__ __align__(16) float uh[23040];   // u_hat [144][160]  (o*16+d)
  __shared__ __align__(16) float us[1152];    // u [144][8]
  __shared__ float blog[1440];                // b [144][10]
  __shared__ float cc[1440];                  // c [144][10]
  __shared__ __align__(16) float vv[160];     // v [10][16]
  __shared__ float ss[160];                   // s [10][16]
  int b = blockIdx.x, t = threadIdx.x;
  for (int i = t; i < 1152; i += 512) us[i] = u[b * 1152 + i];
  for (int i = t; i < 1440; i += 512) blog[i] = 0.0f;
  __syncthreads();
  const float4* W4 = (const float4*)W;
  for (int idx = t; idx < 23040; idx += 512) {
    int i = idx / 160;
    float4 wa = W4[idx * 2], wb = W4[idx * 2 + 1];
    const float4* up = (const float4*)&us[i * 8];
    float4 ua = up[0], ub2 = up[1];
    uh[idx] = wa.x * ua.x + wa.y * ua.y + wa.z * ua.z + wa.w * ua.w +
              wb.x * ub2.x + wb.y * ub2.y + wb.z * ub2.z + wb.w * ub2.w;
  }
  __syncthreads();

  for (int it = 0; it < 3; ++it) {
    if (it > 0) {
      if (t < 144) {
        const float* br = &blog[t * 10];
        float mx = br[0];
#pragma unroll
        for (int o = 1; o < 10; ++o) mx = fmaxf(mx, br[o]);
        float e[10];
        float sum = 0.f;
#pragma unroll
        for (int o = 0; o < 10; ++o) { e[o] = __expf(br[o] - mx); sum += e[o]; }
        float inv = 1.0f / sum;
#pragma unroll
        for (int o = 0; o < 10; ++o) cc[t * 10 + o] = e[o] * inv;
      }
      __syncthreads();
    }
    if (t < 160) {
      int o = t >> 4;
      float acc = 0.f;
      if (it == 0) {
        for (int i = 0; i < 144; ++i) acc += uh[i * 160 + t];
        acc *= 0.1f;
      } else {
        for (int i = 0; i < 144; ++i) acc += cc[i * 10 + o] * uh[i * 160 + t];
      }
      ss[t] = acc;
    }
    __syncthreads();
    if (t < 10) {
      float sq = 0.f;
#pragma unroll
      for (int d = 0; d < 16; ++d) { float x = ss[t * 16 + d]; sq += x * x; }
      float coef = (sq / (1.0f + sq)) / sqrtf(sq + 1e-8f);
#pragma unroll
      for (int d = 0; d < 16; ++d) vv[t * 16 + d] = coef * ss[t * 16 + d];
      if (it == 2) out[b * 10 + t] = coef * sqrtf(sq);
    }
    __syncthreads();
    if (it < 2) {
      for (int idx = t; idx < 1440; idx += 512) {
        int i = idx / 10, o = idx % 10;
        const float4* uhp = (const float4*)&uh[i * 160 + o * 16];
        const float4* vp = (const float4*)&vv[o * 16];
        float dot = 0.f;
#pragma unroll
        for (int q = 0; q < 4; ++q) {
          float4 a = uhp[q], v2 = vp[q];
          dot += a.x * v2.x + a.y * v2.y + a.z * v2.z + a.w * v2.w;
        }
        blog[idx] += dot;
      }
      __syncthreads();
    }
  }
  if (t < 160) out[B * 10 + b * 160 + t] = vv[t];
}

extern "C" void kernel_launch(void* const* d_in, const int* in_sizes, int n_in,
                              void* d_out, int out_size, void* d_ws, size_t ws_size,
                              hipStream_t stream) {
  const float* in = (const float*)d_in[0];
  const float* w1 = (const float*)d_in[1];
  const float* b1 = (const float*)d_in[2];
  const float* w2 = (const float*)d_in[3];
  const float* b2 = (const float*)d_in[4];
  const float* Wr = (const float*)d_in[5];
  float* out = (float*)d_out;
  float* ws = (float*)d_ws;
  int B = in_sizes[0] / 784;

  float* x1 = ws;                       // [B][16][20][20] = B*6400 floats
  float* u  = ws + (size_t)B * 6400;    // [B][144][8]     = B*1152 floats
  float* wT = ws + (size_t)B * 7552;    // [16][9][9][32]  = 41472 floats

  transpose_w2<<<162, 256, 0, stream>>>(w2, wT);
  conv1_kernel<<<B, 320, 0, stream>>>(in, w1, b1, x1);
  conv2_kernel<<<B / 4, 256, 0, stream>>>(x1, wT, b2, u);
  routing_kernel<<<B, 512, 0, stream>>>(u, Wr, out, B);
}